// Round 8
// baseline (1895.206 us; speedup 1.0000x reference)
//
#include <hip/hip_runtime.h>

typedef _Float16 h8 __attribute__((ext_vector_type(8)));
typedef _Float16 h4 __attribute__((ext_vector_type(4)));
typedef float f4 __attribute__((ext_vector_type(4)));

#define SEQ_LEN 50
#define HID 64
#define HS 72   // halves per h row: 144B pitch, 16B-aligned b128 reads

#if __has_builtin(__builtin_amdgcn_exp2f)
#define EXP2(x) __builtin_amdgcn_exp2f(x)
#else
extern "C" __device__ float __ocml_native_exp2_f32(float);
#define EXP2(x) __ocml_native_exp2_f32(x)
#endif
#define RCP(x) __builtin_amdgcn_rcpf(x)

#define LOG2E  1.442695041f
#define LOG2E2 2.885390082f

// BARRIER-FREE design (R8): each wave owns ALL 64 units of its own 16 seqs.
// Block = 256 threads = 4 fully independent waves; NO __syncthreads anywhere.
// h round-trips through a wave-private LDS region; intra-wave LDS RAW is
// ordered by compiler lgkmcnt waits (no s_barrier). Rationale: R5-R7 counters
// show busy cyc strictly proportional to work (~1060/8-tile quantum) with a
// structural ~25% idle pinned across occupancies -> the barrier coupling is
// the prime idle suspect.
//
// Transposed orientation: gates^T = W_ext @ [h; x; 1]. 16 tiles per wave:
// tile(gi,dt) = gate gi (i,f,g,o), unit quarter dt -> rows gi*64+dt*16+(0..15).
// A-frag: lane holds A[m=col][k=quad*8+j]; D: col=seq, row=quad*4+r.
// dt-group processing: 4 live accs (i,f,g,o of units 16dt+quad*4+r).
// x-proj + bias folded into an MFMA with C=0 (Ax nonzero only quad0, k=0,1).
//
// Activations: fused denominators (7 trans + ~15 VALU per unit), pre-scaled
// weights (i,f,o: log2e; g: 2log2e), cell in 2log2e-scaled domain.
//
// Registers: Aw 128 + Ax 64 + acc 16 + c 16 + transients ~25 ~= 250 combined
// -> exactly 2 waves/SIMD (cap 256). Spill gate: FETCH_SIZE must stay ~5e4 KB.
__global__ __launch_bounds__(256, 2)
void lstm_fused(const float* __restrict__ x,
                const float* __restrict__ W_ih,
                const float* __restrict__ W_hh,
                const float* __restrict__ b_ih,
                const float* __restrict__ b_hh,
                const float* __restrict__ W_fc,
                const float* __restrict__ b_fc,
                float* __restrict__ out)
{
    __shared__ _Float16 sH[4][16 * HS];       // per-wave h buffer (single!)
    __shared__ float    sXT[4][SEQ_LEN * 16]; // per-wave x tile, [t][seq]

    const int tid  = threadIdx.x;
    const int wave = tid >> 6;
    const int lane = tid & 63;
    const int col  = lane & 15;
    const int quad = lane >> 4;
    const int seqBase = blockIdx.x * 64 + wave * 16;  // this wave's 16 seqs

    _Float16* hbuf = sH[wave];
    float*    xbuf = sXT[wave];

    // ---- stage x transposed (wave-private): xbuf[t*16+s] = x[(seqBase+s)*50+t]
    for (int i = lane; i < SEQ_LEN * 16; i += 64) {
        const int s = i & 15;
        const int t = i >> 4;
        xbuf[t * 16 + s] = x[(size_t)(seqBase + s) * SEQ_LEN + t];
    }
    // ---- zero h buffer (h0 = 0)
    for (int i = lane; i < 16 * HS; i += 64)
        hbuf[i] = (_Float16)0.0f;

    // ---- W rows as resident fp16 A-fragments, pre-scaled.
    // Aw[gi][dt][kf]: A[m=col][k=quad*8+j] = scale*W_hh[row][kf*32+quad*8+j],
    // row = gi*64 + dt*16 + col.  Ax[gi][dt]: quad0 k=0 -> wih, k=1 -> bias.
    h8 Aw[4][4][2];
    h8 Ax[4][4];
    #pragma unroll
    for (int gi = 0; gi < 4; ++gi) {
        const float scale = (gi == 2) ? LOG2E2 : LOG2E;
        #pragma unroll
        for (int dt = 0; dt < 4; ++dt) {
            const int n = gi * 64 + dt * 16 + col;
            h8 axf = {};
            if (quad == 0) {
                axf[0] = (_Float16)(W_ih[n] * scale);
                axf[1] = (_Float16)((b_ih[n] + b_hh[n]) * scale);
            }
            Ax[gi][dt] = axf;
            #pragma unroll
            for (int kf = 0; kf < 2; ++kf) {
                const float* wp = W_hh + n * HID + kf * 32 + quad * 8;
                f4 lo = *(const f4*)wp;
                f4 hi = *(const f4*)(wp + 4);
                h8 b;
                b[0] = (_Float16)(lo[0] * scale); b[1] = (_Float16)(lo[1] * scale);
                b[2] = (_Float16)(lo[2] * scale); b[3] = (_Float16)(lo[3] * scale);
                b[4] = (_Float16)(hi[0] * scale); b[5] = (_Float16)(hi[1] * scale);
                b[6] = (_Float16)(hi[2] * scale); b[7] = (_Float16)(hi[3] * scale);
                Aw[gi][dt][kf] = b;
            }
        }
    }

    const f4 z4 = {0.0f, 0.0f, 0.0f, 0.0f};

    // cell state c[dt][r] for units 16dt+quad*4+r of seq=col, scaled domain
    float c[4][4];
    #pragma unroll
    for (int dt = 0; dt < 4; ++dt)
        #pragma unroll
        for (int r = 0; r < 4; ++r) c[dt][r] = 0.0f;

    // NO barrier: all state is wave-private.
    for (int t = 0; t < SEQ_LEN; ++t) {
        // B_x = {x_t[seq], 1, 0...}
        h8 bx = {};
        bx[0] = (_Float16)xbuf[t * 16 + col];
        bx[1] = (_Float16)1.0f;

        // B = h^T fragments: B[k=quad*8+j][seq=col] (reads precede writes
        // of this step; compiler orders next step's reads after our writes)
        const _Float16* hp = hbuf + col * HS + quad * 8;
        const h8 Bh0 = *(const h8*)hp;
        const h8 Bh1 = *(const h8*)(hp + 32);

        #pragma unroll
        for (int dt = 0; dt < 4; ++dt) {
            f4 acc[4];
            #pragma unroll
            for (int gi = 0; gi < 4; ++gi) {
                f4 a = __builtin_amdgcn_mfma_f32_16x16x32_f16(Ax[gi][dt], bx, z4, 0, 0, 0);
                a = __builtin_amdgcn_mfma_f32_16x16x32_f16(Aw[gi][dt][0], Bh0, a, 0, 0, 0);
                a = __builtin_amdgcn_mfma_f32_16x16x32_f16(Aw[gi][dt][1], Bh1, a, 0, 0, 0);
                acc[gi] = a;
            }
            // fused-denominator activations: 7 trans + ~15 VALU per unit
            h4 hv;
            #pragma unroll
            for (int r = 0; r < 4; ++r) {
                float Ei = EXP2(-acc[0][r]);
                float Ef = EXP2(-acc[1][r]);
                float Eg = EXP2( acc[2][r]);
                float Eo = EXP2(-acc[3][r]);
                float pi_ = 1.0f + Ei;
                float pf_ = 1.0f + Ef;
                float pg_ = 1.0f + Eg;
                float po_ = 1.0f + Eo;
                float t1  = pi_ * pg_;
                float v   = fmaf(Eg, LOG2E2, -LOG2E2) * pf_;   // L2*(Eg-1)*pf
                float num = fmaf(c[dt][r], t1, v);
                float rc  = RCP(pf_ * t1);
                float cn  = fminf(num * rc, 126.0f);           // overflow guard
                c[dt][r] = cn;
                float Ec  = EXP2(cn);
                float rh  = RCP(po_ * (1.0f + Ec));
                hv[r] = (_Float16)((Ec - 1.0f) * rh);
            }
            // lane's 4 outputs = units 16dt+quad*4+(0..3) of seq=col
            *(h4*)(hbuf + col * HS + dt * 16 + quad * 4) = hv;
        }
    }

    // ---- epilogue (wave-private, no barrier): h[seq][unit] in hbuf
    if (lane < 48) {
        const int sl = lane / 3;
        const int nc = lane % 3;
        const _Float16* hp = hbuf + sl * HS;
        float a = b_fc[nc];
        #pragma unroll
        for (int u = 0; u < HID; ++u)
            a = fmaf((float)hp[u], W_fc[nc * HID + u], a);
        out[(size_t)(seqBase + sl) * 3 + nc] = a;
    }
}

extern "C" void kernel_launch(void* const* d_in, const int* in_sizes, int n_in,
                              void* d_out, int out_size, void* d_ws, size_t ws_size,
                              hipStream_t stream) {
    const float* x    = (const float*)d_in[0];
    const float* W_ih = (const float*)d_in[1];
    const float* W_hh = (const float*)d_in[2];
    const float* b_ih = (const float*)d_in[3];
    const float* b_hh = (const float*)d_in[4];
    const float* W_fc = (const float*)d_in[5];
    const float* b_fc = (const float*)d_in[6];
    float* out = (float*)d_out;

    const int nSeq   = in_sizes[0] / SEQ_LEN;  // 512000
    const int blocks = nSeq / 64;              // 8000 (64 seqs per block)

    hipLaunchKernelGGL(lstm_fused, dim3(blocks), dim3(256), 0, stream,
                       x, W_ih, W_hh, b_ih, b_hh, W_fc, b_fc, out);
}